// Round 1
// baseline (500.680 us; speedup 1.0000x reference)
//
#include <hip/hip_runtime.h>

#define G   100   // number of softmax classes (dim-1)
#define DIM 101
#define R   56
#define L   4
#define RL  224   // R*L

// Block: 256 threads = 4 waves; wave w handles sample n = blockIdx.x*4 + w.
// Within a wave, lane q (q<56) computes pos for positions 4q..4q+3 via
// float4 loads over the 100 channels (stride RL floats).
__global__ __launch_bounds__(256) void pos_loss_kernel(
    const float* __restrict__ x, const int* __restrict__ labels,
    float* __restrict__ ws_total, int* __restrict__ ws_flag)
{
    __shared__ float pos_s[4 * RL];     // [n_sub][r*4+l]
    __shared__ float lane_loss_s[16];   // [n_sub][l]

    const int t     = threadIdx.x;
    const int n_sub = t >> 6;           // 0..3
    const int q     = t & 63;           // 0..63 (active if <56)
    const long long n = (long long)blockIdx.x * 4 + n_sub;

    if (q < 56) {
        const float* xp = x + (size_t)n * DIM * RL + 4 * q;
        float s0 = 0.f, s1 = 0.f, s2 = 0.f, s3 = 0.f;
        float w0 = 0.f, w1 = 0.f, w2 = 0.f, w3 = 0.f;
        #pragma unroll 4
        for (int c = 0; c < G; ++c) {
            float4 v = *(const float4*)(xp + (size_t)c * RL);
            float fc = (float)c;
            float e0 = __expf(v.x);
            float e1 = __expf(v.y);
            float e2 = __expf(v.z);
            float e3 = __expf(v.w);
            s0 += e0; s1 += e1; s2 += e2; s3 += e3;
            w0 = fmaf(fc, e0, w0);
            w1 = fmaf(fc, e1, w1);
            w2 = fmaf(fc, e2, w2);
            w3 = fmaf(fc, e3, w3);
        }
        float* ps = pos_s + n_sub * RL + 4 * q;
        ps[0] = w0 / s0;
        ps[1] = w1 / s1;
        ps[2] = w2 / s2;
        ps[3] = w3 / s3;
    }
    __syncthreads();

    // Bound parsing + masked second-difference sum: one thread per (n_sub, l).
    if (t < 16) {
        const int ns = t >> 2;
        const int l  = t & 3;
        const long long nn = (long long)blockIdx.x * 4 + ns;
        const int* lp = labels + (size_t)nn * RL + l;

        unsigned long long m = 0ull;
        #pragma unroll
        for (int r = 0; r < R; ++r)
            m |= (unsigned long long)(lp[r * 4] < G) << r;

        const unsigned long long MASK55 = (1ull << 55) - 1ull; // bits 0..54
        const bool v0    = (m & 1ull) != 0;
        const bool v1    = (m & 2ull) != 0;
        const bool vlast = ((m >> (R - 1)) & 1ull) != 0;

        unsigned long long up = (~m) & (m >> 1) & MASK55; // bit r: !v[r] & v[r+1]
        unsigned long long dn = m & (~(m >> 1)) & MASK55; // bit r:  v[r] & !v[r+1]
        const bool has_up = (up != 0ull);
        const bool has_dn = (dn != 0ull);
        const int first_up = has_up ? (__builtin_ctzll(up) + 1) : 0;
        const int first_dn = has_dn ? __builtin_ctzll(dn) : 0;

        int  top        = v0 ? 0 : (has_up ? first_up : 0);
        const bool top_exists = v0 || has_up;
        const bool cond0 = v0 && !v1;
        int  down       = cond0 ? 0 : (vlast ? (R - 1) : (has_dn ? first_dn : 0));
        const bool down_exists = cond0 || vlast || has_dn;
        if (!(top_exists && down_exists)) { top = 0; down = 0; }

        const int count = down - top - 1;
        float lane_loss = 0.f;
        if (count >= 1) {
            const float* pr = pos_s + ns * RL + l; // pos[r] at pr[4*r]
            float sum = 0.f;
            const int hi = down - 2; // <= 53
            for (int idx = top; idx <= hi; ++idx) {
                float p0 = pr[4 * idx];
                float p1 = pr[4 * (idx + 1)];
                float p2 = pr[4 * (idx + 2)];
                sum += fabsf(p0 - 2.f * p1 + p2);
            }
            lane_loss = sum / (float)count;
        }
        lane_loss_s[t] = lane_loss;
    }
    __syncthreads();

    if (t < 4) {
        float lk = (lane_loss_s[t * 4 + 0] + lane_loss_s[t * 4 + 1] +
                    lane_loss_s[t * 4 + 2] + lane_loss_s[t * 4 + 3]) * 0.125f;
        if (lk != 0.0f) {
            atomicAdd(ws_total, lk);
            atomicAdd(ws_flag, 1);
        }
    }
}

__global__ void finalize_kernel(const float* __restrict__ ws_total,
                                const int* __restrict__ ws_flag,
                                float* __restrict__ out)
{
    float tot = *ws_total;
    int   f   = *ws_flag;
    out[0] = (f > 0) ? (tot / (float)f) : 0.0f;
}

extern "C" void kernel_launch(void* const* d_in, const int* in_sizes, int n_in,
                              void* d_out, int out_size, void* d_ws, size_t ws_size,
                              hipStream_t stream) {
    const float* x      = (const float*)d_in[0];
    const int*   labels = (const int*)d_in[1];
    float*       out    = (float*)d_out;

    float* ws_total = (float*)d_ws;
    int*   ws_flag  = (int*)((char*)d_ws + sizeof(float));

    // ws is re-poisoned to 0xAA before every launch — zero the accumulators.
    hipMemsetAsync(d_ws, 0, 2 * sizeof(float), stream);

    const int N = in_sizes[1] / RL;   // 4096 samples
    pos_loss_kernel<<<N / 4, 256, 0, stream>>>(x, labels, ws_total, ws_flag);
    finalize_kernel<<<1, 1, 0, stream>>>(ws_total, ws_flag, out);
}

// Round 2
// 488.184 us; speedup vs baseline: 1.0256x; 1.0256x over previous
//
#include <hip/hip_runtime.h>

#define G   100   // number of softmax classes (dim-1)
#define DIM 101
#define R   56
#define L   4
#define RL  224   // R*L
#define NBLK 1024 // 4096 samples / 4 per block

// Block: 256 threads = 4 waves; wave w handles sample n = blockIdx.x*4 + w.
// Within a wave, lane q (q<56) computes pos for positions 4q..4q+3 via
// float4 loads over the 100 channels (stride RL floats).
// Per-block (sum, count) partial is written to ws; no global atomics
// (4096 same-address atomics serialized in TCC -> O(100us) tail in R1).
__global__ __launch_bounds__(256) void pos_loss_kernel(
    const float* __restrict__ x, const int* __restrict__ labels,
    float2* __restrict__ partials)
{
    __shared__ float pos_s[4 * RL];     // [n_sub][r*4+l]
    __shared__ float lane_loss_s[16];   // [n_sub][l]
    __shared__ float blk_red[8];        // [sample] lk, then combine

    const int t     = threadIdx.x;
    const int n_sub = t >> 6;           // 0..3
    const int q     = t & 63;           // 0..63 (active if <56)
    const long long n = (long long)blockIdx.x * 4 + n_sub;

    if (q < 56) {
        const float* xp = x + (size_t)n * DIM * RL + 4 * q;
        float s0 = 0.f, s1 = 0.f, s2 = 0.f, s3 = 0.f;
        float w0 = 0.f, w1 = 0.f, w2 = 0.f, w3 = 0.f;
        #pragma unroll 4
        for (int c = 0; c < G; ++c) {
            float4 v = *(const float4*)(xp + (size_t)c * RL);
            float fc = (float)c;
            float e0 = __expf(v.x);
            float e1 = __expf(v.y);
            float e2 = __expf(v.z);
            float e3 = __expf(v.w);
            s0 += e0; s1 += e1; s2 += e2; s3 += e3;
            w0 = fmaf(fc, e0, w0);
            w1 = fmaf(fc, e1, w1);
            w2 = fmaf(fc, e2, w2);
            w3 = fmaf(fc, e3, w3);
        }
        float* ps = pos_s + n_sub * RL + 4 * q;
        ps[0] = w0 / s0;
        ps[1] = w1 / s1;
        ps[2] = w2 / s2;
        ps[3] = w3 / s3;
    }
    __syncthreads();

    // Bound parsing + masked second-difference sum: one thread per (n_sub, l).
    if (t < 16) {
        const int ns = t >> 2;
        const int l  = t & 3;
        const long long nn = (long long)blockIdx.x * 4 + ns;
        const int* lp = labels + (size_t)nn * RL + l;

        unsigned long long m = 0ull;
        #pragma unroll
        for (int r = 0; r < R; ++r)
            m |= (unsigned long long)(lp[r * 4] < G) << r;

        const unsigned long long MASK55 = (1ull << 55) - 1ull; // bits 0..54
        const bool v0    = (m & 1ull) != 0;
        const bool v1    = (m & 2ull) != 0;
        const bool vlast = ((m >> (R - 1)) & 1ull) != 0;

        unsigned long long up = (~m) & (m >> 1) & MASK55; // bit r: !v[r] & v[r+1]
        unsigned long long dn = m & (~(m >> 1)) & MASK55; // bit r:  v[r] & !v[r+1]
        const bool has_up = (up != 0ull);
        const bool has_dn = (dn != 0ull);
        const int first_up = has_up ? (__builtin_ctzll(up) + 1) : 0;
        const int first_dn = has_dn ? __builtin_ctzll(dn) : 0;

        int  top        = v0 ? 0 : (has_up ? first_up : 0);
        const bool top_exists = v0 || has_up;
        const bool cond0 = v0 && !v1;
        int  down       = cond0 ? 0 : (vlast ? (R - 1) : (has_dn ? first_dn : 0));
        const bool down_exists = cond0 || vlast || has_dn;
        if (!(top_exists && down_exists)) { top = 0; down = 0; }

        const int count = down - top - 1;
        float lane_loss = 0.f;
        if (count >= 1) {
            const float* pr = pos_s + ns * RL + l; // pos[r] at pr[4*r]
            float sum = 0.f;
            const int hi = down - 2; // <= 53
            for (int idx = top; idx <= hi; ++idx) {
                float p0 = pr[4 * idx];
                float p1 = pr[4 * (idx + 1)];
                float p2 = pr[4 * (idx + 2)];
                sum += fabsf(p0 - 2.f * p1 + p2);
            }
            lane_loss = sum / (float)count;
        }
        lane_loss_s[t] = lane_loss;
    }
    __syncthreads();

    if (t < 4) {
        float lk = (lane_loss_s[t * 4 + 0] + lane_loss_s[t * 4 + 1] +
                    lane_loss_s[t * 4 + 2] + lane_loss_s[t * 4 + 3]) * 0.125f;
        blk_red[t]     = lk;                       // sum contribution
        blk_red[t + 4] = (lk != 0.0f) ? 1.f : 0.f; // count contribution
    }
    __syncthreads();

    if (t == 0) {
        float2 p;
        p.x = blk_red[0] + blk_red[1] + blk_red[2] + blk_red[3];
        p.y = blk_red[4] + blk_red[5] + blk_red[6] + blk_red[7];
        partials[blockIdx.x] = p;
    }
}

// Reduce NBLK (sum,count) partials deterministically; one block of 256.
__global__ __launch_bounds__(256) void reduce_kernel(
    const float2* __restrict__ partials, float* __restrict__ out)
{
    __shared__ float sred[4], cred[4];
    const int t = threadIdx.x;
    float s = 0.f, c = 0.f;
    #pragma unroll
    for (int i = 0; i < NBLK / 256; ++i) {
        float2 p = partials[t + i * 256];
        s += p.x;
        c += p.y;
    }
    #pragma unroll
    for (int off = 32; off >= 1; off >>= 1) {
        s += __shfl_down(s, off, 64);
        c += __shfl_down(c, off, 64);
    }
    if ((t & 63) == 0) { sred[t >> 6] = s; cred[t >> 6] = c; }
    __syncthreads();
    if (t == 0) {
        float tot = sred[0] + sred[1] + sred[2] + sred[3];
        float f   = cred[0] + cred[1] + cred[2] + cred[3];
        out[0] = (f > 0.f) ? (tot / f) : 0.0f;
    }
}

extern "C" void kernel_launch(void* const* d_in, const int* in_sizes, int n_in,
                              void* d_out, int out_size, void* d_ws, size_t ws_size,
                              hipStream_t stream) {
    const float* x      = (const float*)d_in[0];
    const int*   labels = (const int*)d_in[1];
    float*       out    = (float*)d_out;
    float2*      partials = (float2*)d_ws;

    const int N = in_sizes[1] / RL;   // 4096 samples
    pos_loss_kernel<<<N / 4, 256, 0, stream>>>(x, labels, partials);
    reduce_kernel<<<1, 256, 0, stream>>>(partials, out);
}

// Round 4
// 455.882 us; speedup vs baseline: 1.0983x; 1.0709x over previous
//
#include <hip/hip_runtime.h>

#define G   100   // number of softmax classes (dim-1)
#define DIM 101
#define R   56
#define L   4
#define RL  224   // R*L
#define NS  4096  // samples

typedef float floatx4 __attribute__((ext_vector_type(4)));

struct Bounds { int top, down, count; };

__device__ __forceinline__ Bounds parse_bounds(unsigned long long m) {
    const unsigned long long MASK55 = (1ull << 55) - 1ull; // bits 0..54
    const bool v0    = (m & 1ull) != 0;
    const bool v1    = (m & 2ull) != 0;
    const bool vlast = ((m >> (R - 1)) & 1ull) != 0;
    unsigned long long up = (~m) & (m >> 1) & MASK55; // bit r: !v[r] & v[r+1]
    unsigned long long dn = m & (~(m >> 1)) & MASK55; // bit r:  v[r] & !v[r+1]
    const bool has_up = (up != 0ull);
    const bool has_dn = (dn != 0ull);
    const int first_up = has_up ? (__builtin_ctzll(up) + 1) : 0;
    const int first_dn = has_dn ? __builtin_ctzll(dn) : 0;
    int top = v0 ? 0 : (has_up ? first_up : 0);
    const bool top_exists = v0 || has_up;
    const bool cond0 = v0 && !v1;
    int down = cond0 ? 0 : (vlast ? (R - 1) : (has_dn ? first_dn : 0));
    const bool down_exists = cond0 || vlast || has_dn;
    if (!(top_exists && down_exists)) { top = 0; down = 0; }
    Bounds b; b.top = top; b.down = down; b.count = down - top - 1;
    return b;
}

// One sample per 128-thread block (2 waves). Wave w streams channels
// [50w, 50w+50); lane q (q<56) owns row r=q (flat positions 4q..4q+3) via
// contiguous float4 nontemporal loads. Wave 1 deposits partial (sum, wsum)
// in LDS; wave 0 combines, then does the whole epilogue wave-synchronously
// with ballot/shuffle (no serial loop, no pos array in LDS).
__global__ __launch_bounds__(128) void pos_loss_kernel(
    const float* __restrict__ x, const int* __restrict__ labels,
    float2* __restrict__ partials)
{
    __shared__ float comb[8][R];  // wave1's s0..3,w0..3, SoA (conflict-free)

    const int t    = threadIdx.x;
    const int wave = t >> 6;      // 0 or 1
    const int q    = t & 63;      // lane
    const int n    = blockIdx.x;  // sample

    float s0 = 0.f, s1 = 0.f, s2 = 0.f, s3 = 0.f;
    float w0 = 0.f, w1 = 0.f, w2 = 0.f, w3 = 0.f;
    if (q < 56) {
        const float* xp = x + (size_t)n * (DIM * RL) + (size_t)(wave * 50) * RL + 4 * q;
        #pragma unroll 5
        for (int c = 0; c < 50; ++c) {
            floatx4 v = __builtin_nontemporal_load((const floatx4*)(xp + (size_t)c * RL));
            float fc = (float)(c + wave * 50);
            float e0 = __expf(v.x);
            float e1 = __expf(v.y);
            float e2 = __expf(v.z);
            float e3 = __expf(v.w);
            s0 += e0; s1 += e1; s2 += e2; s3 += e3;
            w0 = fmaf(fc, e0, w0);
            w1 = fmaf(fc, e1, w1);
            w2 = fmaf(fc, e2, w2);
            w3 = fmaf(fc, e3, w3);
        }
    }

    if (wave == 1 && q < 56) {
        comb[0][q] = s0; comb[1][q] = s1; comb[2][q] = s2; comb[3][q] = s3;
        comb[4][q] = w0; comb[5][q] = w1; comb[6][q] = w2; comb[7][q] = w3;
    }
    __syncthreads();

    if (wave != 0) return;

    float p0 = 0.f, p1 = 0.f, p2 = 0.f, p3 = 0.f;
    int4 lab = make_int4(G, G, G, G);
    if (q < 56) {
        p0 = (w0 + comb[4][q]) / (s0 + comb[0][q]);
        p1 = (w1 + comb[5][q]) / (s1 + comb[1][q]);
        p2 = (w2 + comb[6][q]) / (s2 + comb[2][q]);
        p3 = (w3 + comb[7][q]) / (s3 + comb[3][q]);
        lab = *(const int4*)(labels + (size_t)n * RL + 4 * q);
    }

    // valid masks per l (bit r = labels[n][r][l] < G), lanes >=56 contribute 0
    const bool inrow = (q < 56);
    unsigned long long m0 = __ballot(inrow && (lab.x < G));
    unsigned long long m1 = __ballot(inrow && (lab.y < G));
    unsigned long long m2 = __ballot(inrow && (lab.z < G));
    unsigned long long m3 = __ballot(inrow && (lab.w < G));

    Bounds b0 = parse_bounds(m0);
    Bounds b1 = parse_bounds(m1);
    Bounds b2 = parse_bounds(m2);
    Bounds b3 = parse_bounds(m3);

    // d[r] = pos[r] - pos[r+1]; sec[r] = |d[r] - d[r+1]|  (valid for r<=53)
    float d0 = p0 - __shfl_down(p0, 1, 64);
    float d1 = p1 - __shfl_down(p1, 1, 64);
    float d2 = p2 - __shfl_down(p2, 1, 64);
    float d3 = p3 - __shfl_down(p3, 1, 64);
    float e0 = fabsf(d0 - __shfl_down(d0, 1, 64));
    float e1 = fabsf(d1 - __shfl_down(d1, 1, 64));
    float e2 = fabsf(d2 - __shfl_down(d2, 1, 64));
    float e3 = fabsf(d3 - __shfl_down(d3, 1, 64));

    // masked contributions: idx in [top, down-2] (down-2 <= 53 < 56)
    float c0 = (q >= b0.top && q <= b0.down - 2) ? e0 : 0.f;
    float c1 = (q >= b1.top && q <= b1.down - 2) ? e1 : 0.f;
    float c2 = (q >= b2.top && q <= b2.down - 2) ? e2 : 0.f;
    float c3 = (q >= b3.top && q <= b3.down - 2) ? e3 : 0.f;

    #pragma unroll
    for (int off = 32; off >= 1; off >>= 1) {
        c0 += __shfl_down(c0, off, 64);
        c1 += __shfl_down(c1, off, 64);
        c2 += __shfl_down(c2, off, 64);
        c3 += __shfl_down(c3, off, 64);
    }

    if (q == 0) {
        float ll0 = c0 / fmaxf((float)b0.count, 1.f); // c==0 when mask empty
        float ll1 = c1 / fmaxf((float)b1.count, 1.f);
        float ll2 = c2 / fmaxf((float)b2.count, 1.f);
        float ll3 = c3 / fmaxf((float)b3.count, 1.f);
        float lk = (ll0 + ll1 + ll2 + ll3) * 0.125f;
        partials[n] = make_float2(lk, (lk != 0.0f) ? 1.f : 0.f);
    }
}

// Deterministic reduction of NS (sum,count) partials; one block of 256.
__global__ __launch_bounds__(256) void reduce_kernel(
    const float2* __restrict__ partials, float* __restrict__ out)
{
    __shared__ float sred[4], cred[4];
    const int t = threadIdx.x;
    float s = 0.f, c = 0.f;
    #pragma unroll
    for (int i = 0; i < NS / 256; ++i) {
        float2 p = partials[t + i * 256];
        s += p.x;
        c += p.y;
    }
    #pragma unroll
    for (int off = 32; off >= 1; off >>= 1) {
        s += __shfl_down(s, off, 64);
        c += __shfl_down(c, off, 64);
    }
    if ((t & 63) == 0) { sred[t >> 6] = s; cred[t >> 6] = c; }
    __syncthreads();
    if (t == 0) {
        float tot = sred[0] + sred[1] + sred[2] + sred[3];
        float f   = cred[0] + cred[1] + cred[2] + cred[3];
        out[0] = (f > 0.f) ? (tot / f) : 0.0f;
    }
}

extern "C" void kernel_launch(void* const* d_in, const int* in_sizes, int n_in,
                              void* d_out, int out_size, void* d_ws, size_t ws_size,
                              hipStream_t stream) {
    const float* x        = (const float*)d_in[0];
    const int*   labels   = (const int*)d_in[1];
    float*       out      = (float*)d_out;
    float2*      partials = (float2*)d_ws;

    const int N = in_sizes[1] / RL;   // 4096 samples
    pos_loss_kernel<<<N, 128, 0, stream>>>(x, labels, partials);
    reduce_kernel<<<1, 256, 0, stream>>>(partials, out);
}